// Round 4
// baseline (742.771 us; speedup 1.0000x reference)
//
#include <hip/hip_runtime.h>

// x:   (2,4,8,8,8,96,96) fp32   strides: b 18874368, ci 4718592, cd 589824, t 73728, d 9216, h 96, w 1
// W:   (9,4,4,3,3,3)     fp32
// b:   (9,4)             fp32
// out: (2,4,6,6,8,96,96) fp32
//
// Round-4: round-2 body, __launch_bounds__(256,4) -> (256,8).
// Evidence: OccupancyPercent pinned at ~40% for every (256,4) round
// regardless of LDS (38.4KB->23KB), and 49.7% for the (256,5) round —
// achieved occupancy == 80% of the launch_bounds 2nd arg / 8. The 2nd arg
// is acting as a waves-per-EU CAP on this toolchain. With 23KB LDS and
// 60 VGPRs the HW allows 7 blocks/CU (28 waves); (256,8) uncaps it.
// No prefetch (round-3 proved it neutral; at the 64-VGPR cap it would
// re-create round-1's spill).
//  - LDS row stride 105 (odd): compute reads 2 lanes/bank = conflict-free.
//  - weights from workspace (prep_kernel repack), wave-uniform -> s_load.
//  - staging descriptors precomputed; halo/invalid rows zeroed once.

#define BLOCK 256
#define XSTRIDE 105

__global__ void prep_kernel(const float* __restrict__ Wg,
                            const float* __restrict__ bg,
                            float* __restrict__ ws)
{
    int k = blockIdx.x * blockDim.x + threadIdx.x;
    if (k < 3888) {
        int o  = k & 3;  int r = k >> 2;
        int kw = r % 3;  r /= 3;
        int kh = r % 3;  r /= 3;
        int kd = r % 3;  r /= 3;
        int ij = r % 9;  int ci = r / 9;
        ws[k] = Wg[ij*432 + o*108 + ci*27 + kd*9 + kh*3 + kw];
    }
    if (k < 4) {
        float s = 0.f;
        #pragma unroll
        for (int ij = 0; ij < 9; ++ij) s += bg[ij*4 + k];
        ws[3888 + k] = s * (1.0f / 9.0f);
    }
}

__global__ __launch_bounds__(256, 8) void conv5d_kernel(
    const float* __restrict__ xg,
    const float* __restrict__ wsW,
    float* __restrict__ outg)
{
    __shared__ float xs[54 * XSTRIDE];   // 22680 B -> 7 blocks/CU by LDS

    // zero once: w-halo cols (idx 3 / 100) and out-of-range d/h rows are
    // never re-staged afterwards.
    for (int k = threadIdx.x; k < 54 * XSTRIDE; k += BLOCK) xs[k] = 0.f;

    // XCD-aware block decode: 3456 blocks = 72 (b,c,t) slabs x 48 (d,ht).
    int bi   = blockIdx.x;
    int xcd  = bi & 7;
    int g    = bi >> 3;
    int slab = xcd*9 + g/48;
    int r2   = g % 48;
    int d    = r2 / 6;
    int ht   = r2 % 6;
    int b    = slab / 36;
    int ct   = slab % 36;
    int c    = ct / 6;
    int t    = ct % 6;
    int h0   = ht * 16;

    int wt     = threadIdx.x & 15;   // w0 = 6*wt
    int hr_out = threadIdx.x >> 4;   // 0..15

    // ---- loop-invariant staging descriptors ----
    int  goff[6];
    int  lw[6];
    bool pv[6];
    #pragma unroll
    for (int p = 0; p < 6; ++p) {
        int u   = threadIdx.x + p*BLOCK;   // valid < 1296
        int row = u / 24;
        int q   = u % 24;
        int pl  = row / 18;
        int hr  = row % 18;
        int dd  = d + pl - 1;
        int hh  = h0 + hr - 1;
        pv[p]   = (u < 1296) && ((unsigned)dd < 8u) && ((unsigned)hh < 96u);
        goff[p] = dd*9216 + hh*96 + q*4;
        lw[p]   = row*XSTRIDE + 4 + q*4;
    }

    float acc[4][6] = {};

    #pragma unroll 1
    for (int it = 0; it < 36; ++it) {
        int ci = it / 9;
        int ij = it % 9;
        int i  = ij / 3;
        int j  = ij % 3;
        const float* xp = xg + (size_t)b*18874368 + (size_t)ci*4718592
                             + (size_t)(c + i)*589824
                             + (size_t)(t + j)*73728;

        __syncthreads();   // previous iter's readers done before overwrite

        // ---- stage: issue all 6 global loads, then write to LDS ----
        // (short live range: v[] dies inside this phase)
        float4 v[6];
        #pragma unroll
        for (int p = 0; p < 6; ++p)
            if (pv[p]) v[p] = *(const float4*)(xp + goff[p]);
        #pragma unroll
        for (int p = 0; p < 6; ++p) {
            if (pv[p]) {
                xs[lw[p] + 0] = v[p].x;
                xs[lw[p] + 1] = v[p].y;
                xs[lw[p] + 2] = v[p].z;
                xs[lw[p] + 3] = v[p].w;
            }
        }
        __syncthreads();

        // ---- compute: 9 rows x (3 kw x 6 w x 4 o) = 648 FMAs ----
        const float4* wq4 = (const float4*)(wsW + (ci*9 + ij)*108);
        #pragma unroll
        for (int pl = 0; pl < 3; ++pl) {
            #pragma unroll
            for (int kh = 0; kh < 3; ++kh) {
                const float* xr = &xs[(pl*18 + hr_out + kh)*XSTRIDE + 3 + 6*wt];
                float x0 = xr[0], x1 = xr[1], x2 = xr[2], x3 = xr[3];
                float x4 = xr[4], x5 = xr[5], x6 = xr[6], x7 = xr[7];
                float xv[8] = {x0, x1, x2, x3, x4, x5, x6, x7};
                const float4* wr = wq4 + (pl*3 + kh)*3;
                float4 wk0 = wr[0];
                float4 wk1 = wr[1];
                float4 wk2 = wr[2];
                #pragma unroll
                for (int vv = 0; vv < 6; ++vv) {
                    float a = xv[vv], bb = xv[vv+1], cc = xv[vv+2];
                    acc[0][vv] = fmaf(a,  wk0.x, acc[0][vv]);
                    acc[1][vv] = fmaf(a,  wk0.y, acc[1][vv]);
                    acc[2][vv] = fmaf(a,  wk0.z, acc[2][vv]);
                    acc[3][vv] = fmaf(a,  wk0.w, acc[3][vv]);
                    acc[0][vv] = fmaf(bb, wk1.x, acc[0][vv]);
                    acc[1][vv] = fmaf(bb, wk1.y, acc[1][vv]);
                    acc[2][vv] = fmaf(bb, wk1.z, acc[2][vv]);
                    acc[3][vv] = fmaf(bb, wk1.w, acc[3][vv]);
                    acc[0][vv] = fmaf(cc, wk2.x, acc[0][vv]);
                    acc[1][vv] = fmaf(cc, wk2.y, acc[1][vv]);
                    acc[2][vv] = fmaf(cc, wk2.z, acc[2][vv]);
                    acc[3][vv] = fmaf(cc, wk2.w, acc[3][vv]);
                }
            }
        }
    }

    float4 mb4 = *(const float4*)(wsW + 3888);
    float mb[4] = {mb4.x, mb4.y, mb4.z, mb4.w};

    const float inv9 = 1.0f / 9.0f;
    size_t obase = (size_t)b*10616832 + (size_t)c*442368 + (size_t)t*73728
                 + (size_t)d*9216 + (size_t)(h0 + hr_out)*96 + 6*wt;
    #pragma unroll
    for (int o = 0; o < 4; ++o) {
        float* op = outg + obase + (size_t)o*2654208;
        #pragma unroll
        for (int vv = 0; vv < 3; ++vv) {
            float2 st;
            st.x = acc[o][2*vv]   * inv9 + mb[o];
            st.y = acc[o][2*vv+1] * inv9 + mb[o];
            *(float2*)(op + 2*vv) = st;
        }
    }
}

extern "C" void kernel_launch(void* const* d_in, const int* in_sizes, int n_in,
                              void* d_out, int out_size, void* d_ws, size_t ws_size,
                              hipStream_t stream) {
    const float* x = (const float*)d_in[0];
    const float* W = (const float*)d_in[1];
    const float* b = (const float*)d_in[2];
    float* out = (float*)d_out;
    float* ws  = (float*)d_ws;

    prep_kernel<<<16, BLOCK, 0, stream>>>(W, b, ws);
    conv5d_kernel<<<3456, BLOCK, 0, stream>>>(x, ws, out);
}